// Round 3
// baseline (208.635 us; speedup 1.0000x reference)
//
#include <hip/hip_runtime.h>
#include <math.h>

// GRNN Kalman scan, chunked-affine-scan, R2.
// R2 changes vs R1:
//  - phase A inner loop: 11 VALU/step, critical cycle = 2 FMA (vx->t1->nvx);
//    vp chain flattened via cxp^2.
//  - phase BCD: dy0 staged to LDS transposed [pos][chunk] (pad 65) so global
//    access is fully coalesced float4 and per-chunk walks are conflict-free
//    LDS column reads; dy_hat written back in place and staged out coalesced.

constexpr int T = 4096;
constexpr int B = 512;
constexpr int CH = 64;      // steps per chunk
constexpr int NC = T / CH;  // 64 chunks

// ws layout (float offsets):
//   [0, 16384)      Ttab  float4[T]  {T00, T10, g0, g1}
//   [16384, 24576)  Htab  float2[T]  {h0, h1}
//   [24576, 24832)  Ptab  float4[NC] {p00, p01, p10, p11}
//   [24832, 24836)  fin   float4     {vx_f, vp_f, cxp_f, t_f}
constexpr int WS_T = 0;
constexpr int WS_H = 16384;
constexpr int WS_P = 24576;
constexpr int WS_F = 24832;

__global__ __launch_bounds__(64) void grnn_phaseA(
    const float* __restrict__ state0,
    const float* __restrict__ omega_p,
    float* __restrict__ ws)
{
    __shared__ float2 scov[T];  // 32 KB: (vx_t, cxp_t) pre-update
    const int lane = threadIdx.x;

    const float DT = 0.001f;
    const float w  = omega_p[0];
    const float k1 = 1.0f + DT * (-0.3f);   // 1 + DT*2a
    const float k2 = DT * 2.0f * w;
    const float k3 = DT * 1.65f;            // DT*Dd
    const float k4 = DT * 2.88f;            // DT*c2
    const float kw = DT * w;
    const float kA = 1.0f + DT * (-0.15f);  // 1 + DT*a
    const float cc = 1.69705627484771f;     // sqrt(2.88)
    const float nk4 = -k4, nk2 = -k2, kwn = -kw;

    if (lane == 0) {
        float vx = state0[2], vp = state0[3], cxp = state0[4], t = state0[5];
        #pragma unroll 8
        for (int tt = 0; tt < T; ++tt) {
            scov[tt] = make_float2(vx, cxp);
            const float t1   = fmaf(nk4, vx, k1);    // dep: vx (chain 1)
            const float s1   = fmaf(k2, cxp, k3);
            const float mvx  = kwn * vx;
            const float m    = fmaf(kw, vp, mvx);
            const float cxp2 = cxp * cxp;
            const float uu   = fmaf(nk2, cxp, k3);
            const float in2  = fmaf(nk4, cxp2, uu);
            const float nvp  = fmaf(k1, vp, in2);
            const float nvx  = fmaf(t1, vx, s1);     // dep: t1 (chain 2)
            const float ncx  = fmaf(t1, cxp, m);
            vx = nvx; cxp = ncx; vp = nvp;
            t += DT;   // replicate reference's sequential fp32 accumulation
        }
        *(float4*)(ws + WS_F) = make_float4(vx, vp, cxp, t);
    }
    __syncthreads();

    // Backward pass over this lane's chunk: H_t = R * g_t, R <- R * T_t.
    float r00 = 1.f, r01 = 0.f, r10 = 0.f, r11 = 1.f;
    const int c = lane;
    float4* Ttab = (float4*)(ws + WS_T);
    float2* Htab = (float2*)(ws + WS_H);
    #pragma unroll 4
    for (int j = CH - 1; j >= 0; --j) {
        const int t = c * CH + j;
        const float2 vc = scov[t];
        const float T00 = fmaf(nk4, vc.x, kA);
        const float T10 = fmaf(nk4, vc.y, -kw);
        const float g0  = cc * vc.x;
        const float g1  = cc * vc.y;
        Htab[t] = make_float2(fmaf(r00, g0, r01 * g1), fmaf(r10, g0, r11 * g1));
        Ttab[t] = make_float4(T00, T10, g0, g1);
        const float n00 = fmaf(r00, T00, r01 * T10);
        const float n01 = fmaf(r00, kw,  r01 * kA);
        const float n10 = fmaf(r10, T00, r11 * T10);
        const float n11 = fmaf(r10, kw,  r11 * kA);
        r00 = n00; r01 = n01; r10 = n10; r11 = n11;
    }
    ((float4*)(ws + WS_P))[c] = make_float4(r00, r01, r10, r11);
}

__global__ __launch_bounds__(64) void grnn_phaseBCD(
    const float* __restrict__ dy,
    const float* __restrict__ state0,
    const float* __restrict__ omega_p,
    float* __restrict__ out,
    const float* __restrict__ ws)
{
    // sbuf[j][c]: value at chunk c, position j (transposed, pad 65 vs 64).
    __shared__ float sbuf[CH * 65];
    const int b = blockIdx.x;
    const int lane = threadIdx.x;   // chunk index in phases B..D
    const int c = lane;

    const float DT = 0.001f;
    const float w  = omega_p[0];
    const float kw = DT * w;
    const float kA = 1.0f + DT * (-0.15f);
    const float cc = 1.69705627484771f;
    const float kcDT = cc * DT;

    const float4* Ttab = (const float4*)(ws + WS_T);
    const float4* H4   = (const float4*)(ws + WS_H);  // 2 timesteps per float4

    // ---- Stage in: coalesced float4 global -> LDS transposed ----
    const float* dyb = dy + (size_t)b * (T * 2);
    #pragma unroll 4
    for (int k = 0; k < 32; ++k) {
        const float4 d = *(const float4*)(dyb + 4 * (k * 64 + lane));
        const int t0 = k * 128 + 2 * lane;   // this float4 covers t0, t0+1
        const int j0 = t0 & 63;
        const int c0 = t0 >> 6;
        sbuf[j0 * 65 + c0]       = d.x;      // dy[:,t0,0]
        sbuf[(j0 + 1) * 65 + c0] = d.z;      // dy[:,t0+1,0]
    }
    __syncthreads();

    // ---- Phase B: q_c = sum_t H_t * dy0 ----
    float q0 = 0.f, q1 = 0.f;
    #pragma unroll 8
    for (int j = 0; j < CH; j += 2) {
        const float d0 = sbuf[j * 65 + c];
        const float d1 = sbuf[(j + 1) * 65 + c];
        const float4 h = H4[(c * CH + j) >> 1];
        q0 = fmaf(h.x, d0, q0);
        q1 = fmaf(h.y, d0, q1);
        q0 = fmaf(h.z, d1, q0);
        q1 = fmaf(h.w, d1, q1);
    }
    const float4 Pv = ((const float4*)(ws + WS_P))[c];
    float p00 = Pv.x, p01 = Pv.y, p10 = Pv.z, p11 = Pv.w;

    // ---- Phase C: inclusive Hillis-Steele scan of affine maps (P,q) ----
    for (int d = 1; d < 64; d <<= 1) {
        const float o00 = __shfl_up(p00, d), o01 = __shfl_up(p01, d);
        const float o10 = __shfl_up(p10, d), o11 = __shfl_up(p11, d);
        const float oq0 = __shfl_up(q0, d),  oq1 = __shfl_up(q1, d);
        if (c >= d) {
            const float n00 = fmaf(p00, o00, p01 * o10);
            const float n01 = fmaf(p00, o01, p01 * o11);
            const float n10 = fmaf(p10, o00, p11 * o10);
            const float n11 = fmaf(p10, o01, p11 * o11);
            const float nq0 = fmaf(p00, oq0, fmaf(p01, oq1, q0));
            const float nq1 = fmaf(p10, oq0, fmaf(p11, oq1, q1));
            p00 = n00; p01 = n01; p10 = n10; p11 = n11;
            q0 = nq0; q1 = nq1;
        }
    }
    float e00 = __shfl_up(p00, 1), e01 = __shfl_up(p01, 1);
    float e10 = __shfl_up(p10, 1), e11 = __shfl_up(p11, 1);
    float eq0 = __shfl_up(q0, 1),  eq1 = __shfl_up(q1, 1);
    if (c == 0) { e00 = 1.f; e01 = 0.f; e10 = 0.f; e11 = 1.f; eq0 = 0.f; eq1 = 0.f; }

    const float xi0 = state0[b * 6 + 0];
    const float xi1 = state0[b * 6 + 1];
    float x0 = fmaf(e00, xi0, fmaf(e01, xi1, eq0));
    float x1 = fmaf(e10, xi0, fmaf(e11, xi1, eq1));

    // ---- Phase D: re-walk chunk from LDS; write h back in place ----
    #pragma unroll 8
    for (int j = 0; j < CH; j += 2) {
        const int t = c * CH + j;
        const float d0 = sbuf[j * 65 + c];
        const float d1 = sbuf[(j + 1) * 65 + c];
        const float4 T0 = Ttab[t];
        const float4 T1 = Ttab[t + 1];
        const float h0  = kcDT * x0;
        const float nx0 = fmaf(T0.x, x0, fmaf(kw, x1, T0.z * d0));
        const float nx1 = fmaf(T0.y, x0, fmaf(kA, x1, T0.w * d0));
        const float h1  = kcDT * nx0;
        const float mx0 = fmaf(T1.x, nx0, fmaf(kw, nx1, T1.z * d1));
        const float mx1 = fmaf(T1.y, nx0, fmaf(kA, nx1, T1.w * d1));
        sbuf[j * 65 + c]       = h0;
        sbuf[(j + 1) * 65 + c] = h1;
        x0 = mx0; x1 = mx1;
    }

    if (c == 63) {
        const float4 fin = *(const float4*)(ws + WS_F);
        float* os = out + b * 6;
        os[0] = x0;    os[1] = x1;
        os[2] = fin.x; os[3] = fin.y; os[4] = fin.z; os[5] = fin.w;
    }
    __syncthreads();

    // ---- Stage out: LDS -> coalesced float4 global (h, 0, h, 0) ----
    float* dyh = out + B * 6 + (size_t)b * (T * 2);
    #pragma unroll 4
    for (int k = 0; k < 32; ++k) {
        const int t0 = k * 128 + 2 * lane;
        const int j0 = t0 & 63;
        const int c0 = t0 >> 6;
        const float h0 = sbuf[j0 * 65 + c0];
        const float h1 = sbuf[(j0 + 1) * 65 + c0];
        *(float4*)(dyh + 4 * (k * 64 + lane)) = make_float4(h0, 0.f, h1, 0.f);
    }
}

extern "C" void kernel_launch(void* const* d_in, const int* in_sizes, int n_in,
                              void* d_out, int out_size, void* d_ws, size_t ws_size,
                              hipStream_t stream) {
    const float* dy     = (const float*)d_in[0];
    const float* state0 = (const float*)d_in[1];
    const float* omega  = (const float*)d_in[2];
    float* out = (float*)d_out;
    float* ws  = (float*)d_ws;
    grnn_phaseA<<<1, 64, 0, stream>>>(state0, omega, ws);
    grnn_phaseBCD<<<B, 64, 0, stream>>>(dy, state0, omega, out, ws);
}

// Round 4
// 117.607 us; speedup vs baseline: 1.7740x; 1.7740x over previous
//
#include <hip/hip_runtime.h>
#include <math.h>

// GRNN Kalman scan, R3.
// Phase A: multiple-shooting Newton across 64 chunk boundaries (lane=chunk).
//   predictor: 64 coarse Euler steps (dt=64*DT); then NSWEEP Newton sweeps:
//   each lane integrates its chunk carrying the 3x3 Jacobian product,
//   defect d_c = Phi(S_c) - S_{c+1}, affine wave-scan solves E, S += E.
//   Final pass re-integrates, writes scovT to LDS transposed, backward pass
//   emits TtabT/HtabT/Ptab with [j*64+c] layout (coalesced in both kernels).
//   Wave 1 lane 0 concurrently replicates the serial fp32 t += DT chain.
// Phase BCD: as R2 (LDS-transposed dy) but table reads now coalesced.

constexpr int T = 4096;
constexpr int B = 512;
constexpr int CH = 64;      // steps per chunk
constexpr int NC = T / CH;  // 64 chunks
constexpr int NSWEEP = 5;

// ws layout (float offsets), tables TRANSPOSED to [j*64 + c]:
constexpr int WS_T = 0;       // TtabT float4[T]  {T00,T10,g0,g1}
constexpr int WS_H = 16384;   // HtabT float2[T]  {h0,h1}
constexpr int WS_P = 24576;   // Ptab  float4[NC]
constexpr int WS_F = 24832;   // fin   {vx,vp,cxp,t}

__global__ __launch_bounds__(128) void grnn_phaseA(
    const float* __restrict__ state0,
    const float* __restrict__ omega_p,
    float* __restrict__ ws)
{
    __shared__ float2 scovT[T];  // 32 KB, [j*64+c]
    const int tid = threadIdx.x;

    const float DT = 0.001f;
    const float w  = omega_p[0];
    const float k1 = 1.0f + DT * (-0.3f);   // 1 + 2a*DT
    const float k2 = DT * 2.0f * w;
    const float k3 = DT * 1.65f;
    const float k4 = DT * 2.88f;
    const float kw = DT * w;
    const float kA = 1.0f + DT * (-0.15f);  // 1 + a*DT
    const float cc = 1.69705627484771f;     // sqrt(2.88)
    const float nk4 = -k4, n2k4 = -2.0f * k4;

    if (tid >= 64) {
        if (tid == 64) {   // replicate reference's sequential fp32 t accumulation
            float t = state0[5];
            for (int i = 0; i < T; ++i) t += DT;
            ws[WS_F + 3] = t;
        }
    } else {
        const int c = tid;
        // ---- predictor: coarse Euler (dt = CH*DT), snapshot at step c ----
        const float dtc = (float)CH * DT;
        float vx = state0[2], vp = state0[3], cx = state0[4];
        float S0 = vx, S1 = vp, S2 = cx;
        for (int i = 0; i < NC; ++i) {
            if (i == c) { S0 = vx; S1 = vp; S2 = cx; }
            const float fvx = fmaf(-2.88f, vx * vx, fmaf(-0.3f, vx, fmaf(2.0f * w, cx, 1.65f)));
            const float fvp = fmaf(-2.88f, cx * cx, fmaf(-0.3f, vp, fmaf(-2.0f * w, cx, 1.65f)));
            const float fcx = fmaf(-2.88f, vx * cx, fmaf(-0.3f, cx, w * (vp - vx)));
            vx = fmaf(dtc, fvx, vx);
            vp = fmaf(dtc, fvp, vp);
            cx = fmaf(dtc, fcx, cx);
        }

        // ---- Newton sweeps ----
        for (int sw = 0; sw < NSWEEP; ++sw) {
            float vx0 = S0, vp0 = S1, cx0 = S2;
            float m00 = 1.f, m01 = 0.f, m02 = 0.f;
            float m10 = 0.f, m11 = 1.f, m12 = 0.f;
            float m20 = 0.f, m21 = 0.f, m22 = 1.f;
            #pragma unroll 4
            for (int j = 0; j < CH; ++j) {
                // Jacobian of F at current state (J01=J10=0, J02=k2, J11=k1, J21=kw)
                const float J00 = fmaf(n2k4, vx0, k1);
                const float J12 = fmaf(n2k4, cx0, -k2);
                const float J20 = fmaf(nk4, cx0, -kw);
                const float J22 = fmaf(nk4, vx0, k1);
                // M <- J*M
                const float a00 = fmaf(J00, m00, k2 * m20);
                const float a01 = fmaf(J00, m01, k2 * m21);
                const float a02 = fmaf(J00, m02, k2 * m22);
                const float a10 = fmaf(k1, m10, J12 * m20);
                const float a11 = fmaf(k1, m11, J12 * m21);
                const float a12 = fmaf(k1, m12, J12 * m22);
                const float a20 = fmaf(J20, m00, fmaf(kw, m10, J22 * m20));
                const float a21 = fmaf(J20, m01, fmaf(kw, m11, J22 * m21));
                const float a22 = fmaf(J20, m02, fmaf(kw, m12, J22 * m22));
                m00 = a00; m01 = a01; m02 = a02;
                m10 = a10; m11 = a11; m12 = a12;
                m20 = a20; m21 = a21; m22 = a22;
                // exact Euler step F (same op order as serial reference kernel)
                const float t1   = fmaf(nk4, vx0, k1);
                const float s1   = fmaf(k2, cx0, k3);
                const float mvx  = -kw * vx0;
                const float mm   = fmaf(kw, vp0, mvx);
                const float cxp2 = cx0 * cx0;
                const float uu   = fmaf(-k2, cx0, k3);
                const float in2  = fmaf(nk4, cxp2, uu);
                const float nvp  = fmaf(k1, vp0, in2);
                const float nvx  = fmaf(t1, vx0, s1);
                const float ncx  = fmaf(t1, cx0, mm);
                vx0 = nvx; cx0 = ncx; vp0 = nvp;
            }
            // defect d_c = Phi(S_c) - S_{c+1}
            float d0 = vx0 - __shfl_down(S0, 1);
            float d1 = vp0 - __shfl_down(S1, 1);
            float d2 = cx0 - __shfl_down(S2, 1);
            if (c == 63) { d0 = 0.f; d1 = 0.f; d2 = 0.f; }
            // affine scan over lanes: (M, d) composition, self AFTER other
            for (int k = 1; k < 64; k <<= 1) {
                const float o00 = __shfl_up(m00, k), o01 = __shfl_up(m01, k), o02 = __shfl_up(m02, k);
                const float o10 = __shfl_up(m10, k), o11 = __shfl_up(m11, k), o12 = __shfl_up(m12, k);
                const float o20 = __shfl_up(m20, k), o21 = __shfl_up(m21, k), o22 = __shfl_up(m22, k);
                const float e0  = __shfl_up(d0, k),  e1  = __shfl_up(d1, k),  e2  = __shfl_up(d2, k);
                if (c >= k) {
                    const float b00 = fmaf(m00, o00, fmaf(m01, o10, m02 * o20));
                    const float b01 = fmaf(m00, o01, fmaf(m01, o11, m02 * o21));
                    const float b02 = fmaf(m00, o02, fmaf(m01, o12, m02 * o22));
                    const float b10 = fmaf(m10, o00, fmaf(m11, o10, m12 * o20));
                    const float b11 = fmaf(m10, o01, fmaf(m11, o11, m12 * o21));
                    const float b12 = fmaf(m10, o02, fmaf(m11, o12, m12 * o22));
                    const float b20 = fmaf(m20, o00, fmaf(m21, o10, m22 * o20));
                    const float b21 = fmaf(m20, o01, fmaf(m21, o11, m22 * o21));
                    const float b22 = fmaf(m20, o02, fmaf(m21, o12, m22 * o22));
                    const float nd0 = fmaf(m00, e0, fmaf(m01, e1, fmaf(m02, e2, d0)));
                    const float nd1 = fmaf(m10, e0, fmaf(m11, e1, fmaf(m12, e2, d1)));
                    const float nd2 = fmaf(m20, e0, fmaf(m21, e1, fmaf(m22, e2, d2)));
                    m00 = b00; m01 = b01; m02 = b02;
                    m10 = b10; m11 = b11; m12 = b12;
                    m20 = b20; m21 = b21; m22 = b22;
                    d0 = nd0; d1 = nd1; d2 = nd2;
                }
            }
            // E_c = inclusive q of lane c-1; lane 0 -> 0. Update boundaries.
            float E0 = __shfl_up(d0, 1), E1 = __shfl_up(d1, 1), E2 = __shfl_up(d2, 1);
            if (c == 0) { E0 = 0.f; E1 = 0.f; E2 = 0.f; }
            S0 += E0; S1 += E1; S2 += E2;
        }

        // ---- final pass: write scovT (transposed), final state from lane 63
        float vx0 = S0, vp0 = S1, cx0 = S2;
        #pragma unroll 4
        for (int j = 0; j < CH; ++j) {
            scovT[j * 64 + c] = make_float2(vx0, cx0);
            const float t1   = fmaf(nk4, vx0, k1);
            const float s1   = fmaf(k2, cx0, k3);
            const float mvx  = -kw * vx0;
            const float mm   = fmaf(kw, vp0, mvx);
            const float cxp2 = cx0 * cx0;
            const float uu   = fmaf(-k2, cx0, k3);
            const float in2  = fmaf(nk4, cxp2, uu);
            const float nvp  = fmaf(k1, vp0, in2);
            const float nvx  = fmaf(t1, vx0, s1);
            const float ncx  = fmaf(t1, cx0, mm);
            vx0 = nvx; cx0 = ncx; vp0 = nvp;
        }
        if (c == 63) { ws[WS_F] = vx0; ws[WS_F + 1] = vp0; ws[WS_F + 2] = cx0; }
    }
    __syncthreads();

    if (tid < 64) {
        const int c = tid;
        float r00 = 1.f, r01 = 0.f, r10 = 0.f, r11 = 1.f;
        float4* TtabT = (float4*)(ws + WS_T);
        float2* HtabT = (float2*)(ws + WS_H);
        #pragma unroll 4
        for (int j = CH - 1; j >= 0; --j) {
            const float2 vc = scovT[j * 64 + c];
            const float T00 = fmaf(nk4, vc.x, kA);
            const float T10 = fmaf(nk4, vc.y, -kw);
            const float g0  = cc * vc.x;
            const float g1  = cc * vc.y;
            HtabT[j * 64 + c] = make_float2(fmaf(r00, g0, r01 * g1), fmaf(r10, g0, r11 * g1));
            TtabT[j * 64 + c] = make_float4(T00, T10, g0, g1);
            const float n00 = fmaf(r00, T00, r01 * T10);
            const float n01 = fmaf(r00, kw,  r01 * kA);
            const float n10 = fmaf(r10, T00, r11 * T10);
            const float n11 = fmaf(r10, kw,  r11 * kA);
            r00 = n00; r01 = n01; r10 = n10; r11 = n11;
        }
        ((float4*)(ws + WS_P))[c] = make_float4(r00, r01, r10, r11);
    }
}

__global__ __launch_bounds__(64) void grnn_phaseBCD(
    const float* __restrict__ dy,
    const float* __restrict__ state0,
    const float* __restrict__ omega_p,
    float* __restrict__ out,
    const float* __restrict__ ws)
{
    __shared__ float sbuf[CH * 65];   // [j][c], pad 65
    const int b = blockIdx.x;
    const int lane = threadIdx.x;
    const int c = lane;

    const float DT = 0.001f;
    const float w  = omega_p[0];
    const float kw = DT * w;
    const float kA = 1.0f + DT * (-0.15f);
    const float cc = 1.69705627484771f;
    const float kcDT = cc * DT;

    const float4* TtabT = (const float4*)(ws + WS_T);
    const float2* HtabT = (const float2*)(ws + WS_H);

    // ---- Stage in: coalesced float4 global -> LDS transposed ----
    const float* dyb = dy + (size_t)b * (T * 2);
    #pragma unroll 4
    for (int k = 0; k < 32; ++k) {
        const float4 d = *(const float4*)(dyb + 4 * (k * 64 + lane));
        const int t0 = k * 128 + 2 * lane;
        const int j0 = t0 & 63;
        const int c0 = t0 >> 6;
        sbuf[j0 * 65 + c0]       = d.x;
        sbuf[(j0 + 1) * 65 + c0] = d.z;
    }
    __syncthreads();

    // ---- Phase B: q_c = sum_j H_j * dy0 (coalesced HtabT reads) ----
    float q0 = 0.f, q1 = 0.f;
    #pragma unroll 8
    for (int j = 0; j < CH; ++j) {
        const float d0 = sbuf[j * 65 + c];
        const float2 h = HtabT[j * 64 + c];
        q0 = fmaf(h.x, d0, q0);
        q1 = fmaf(h.y, d0, q1);
    }
    const float4 Pv = ((const float4*)(ws + WS_P))[c];
    float p00 = Pv.x, p01 = Pv.y, p10 = Pv.z, p11 = Pv.w;

    // ---- Phase C: wave scan of affine maps (P,q) ----
    for (int d = 1; d < 64; d <<= 1) {
        const float o00 = __shfl_up(p00, d), o01 = __shfl_up(p01, d);
        const float o10 = __shfl_up(p10, d), o11 = __shfl_up(p11, d);
        const float oq0 = __shfl_up(q0, d),  oq1 = __shfl_up(q1, d);
        if (c >= d) {
            const float n00 = fmaf(p00, o00, p01 * o10);
            const float n01 = fmaf(p00, o01, p01 * o11);
            const float n10 = fmaf(p10, o00, p11 * o10);
            const float n11 = fmaf(p10, o01, p11 * o11);
            const float nq0 = fmaf(p00, oq0, fmaf(p01, oq1, q0));
            const float nq1 = fmaf(p10, oq0, fmaf(p11, oq1, q1));
            p00 = n00; p01 = n01; p10 = n10; p11 = n11;
            q0 = nq0; q1 = nq1;
        }
    }
    float e00 = __shfl_up(p00, 1), e01 = __shfl_up(p01, 1);
    float e10 = __shfl_up(p10, 1), e11 = __shfl_up(p11, 1);
    float eq0 = __shfl_up(q0, 1),  eq1 = __shfl_up(q1, 1);
    if (c == 0) { e00 = 1.f; e01 = 0.f; e10 = 0.f; e11 = 1.f; eq0 = 0.f; eq1 = 0.f; }

    const float xi0 = state0[b * 6 + 0];
    const float xi1 = state0[b * 6 + 1];
    float x0 = fmaf(e00, xi0, fmaf(e01, xi1, eq0));
    float x1 = fmaf(e10, xi0, fmaf(e11, xi1, eq1));

    // ---- Phase D: re-walk chunk (coalesced TtabT reads); h back in place ----
    #pragma unroll 4
    for (int j = 0; j < CH; ++j) {
        const float d0 = sbuf[j * 65 + c];
        const float4 Tt = TtabT[j * 64 + c];
        const float h0  = kcDT * x0;
        const float nx0 = fmaf(Tt.x, x0, fmaf(kw, x1, Tt.z * d0));
        const float nx1 = fmaf(Tt.y, x0, fmaf(kA, x1, Tt.w * d0));
        sbuf[j * 65 + c] = h0;
        x0 = nx0; x1 = nx1;
    }

    if (c == 63) {
        float* os = out + b * 6;
        os[0] = x0;          os[1] = x1;
        os[2] = ws[WS_F];    os[3] = ws[WS_F + 1];
        os[4] = ws[WS_F + 2]; os[5] = ws[WS_F + 3];
    }
    __syncthreads();

    // ---- Stage out: LDS -> coalesced float4 global (h, 0, h, 0) ----
    float* dyh = out + B * 6 + (size_t)b * (T * 2);
    #pragma unroll 4
    for (int k = 0; k < 32; ++k) {
        const int t0 = k * 128 + 2 * lane;
        const int j0 = t0 & 63;
        const int c0 = t0 >> 6;
        const float h0 = sbuf[j0 * 65 + c0];
        const float h1 = sbuf[(j0 + 1) * 65 + c0];
        *(float4*)(dyh + 4 * (k * 64 + lane)) = make_float4(h0, 0.f, h1, 0.f);
    }
}

extern "C" void kernel_launch(void* const* d_in, const int* in_sizes, int n_in,
                              void* d_out, int out_size, void* d_ws, size_t ws_size,
                              hipStream_t stream) {
    const float* dy     = (const float*)d_in[0];
    const float* state0 = (const float*)d_in[1];
    const float* omega  = (const float*)d_in[2];
    float* out = (float*)d_out;
    float* ws  = (float*)d_ws;
    grnn_phaseA<<<1, 128, 0, stream>>>(state0, omega, ws);
    grnn_phaseBCD<<<B, 64, 0, stream>>>(dy, state0, omega, out, ws);
}

// Round 5
// 91.590 us; speedup vs baseline: 2.2779x; 1.2841x over previous
//
#include <hip/hip_runtime.h>
#include <math.h>

// GRNN Kalman scan, R4: CH=16, NC=256 everywhere; 3 Newton sweeps; closed-form t.
// Phase A (1 block x 256): two-level predictor -> 3 multiple-shooting Newton
//   sweeps (16-step chunks, 3x3 Jacobian, two-level 256-lane affine scan) ->
//   final pass writes scovT[j*256+c] (LDS) -> backward pass emits
//   TtabT/HtabT/Ptab (coalesced [j*256+c] layout) to ws.
// Phase BCD (512 blocks x 256): stage dy0 to LDS transposed (stride 258),
//   q-reduction (16 steps), two-level 2x2 affine scan, 16-step re-walk
//   writing dy_hat, coalesced stage-out.

constexpr int T = 4096;
constexpr int B = 512;
constexpr int CH = 16;       // steps per chunk
constexpr int NC = T / CH;   // 256 chunks
constexpr int NSWEEP = 3;
constexpr int SB = 258;      // sbuf stride: (2j+c) mod 32 -> max 2-way (free)

// ws layout (float offsets), tables [j*256 + c]:
constexpr int WS_T = 0;        // TtabT float4[T] {T00,T10,g0,g1}
constexpr int WS_H = 16384;    // HtabT float2[T] {h0,h1}
constexpr int WS_P = 24576;    // Ptab  float4[NC]
constexpr int WS_F = 25600;    // fin   {vx,vp,cxp,t}

__global__ __launch_bounds__(256) void grnn_phaseA(
    const float* __restrict__ state0,
    const float* __restrict__ omega_p,
    float* __restrict__ ws)
{
    __shared__ float2 scovT[T];      // 32 KB, [j*256+c]
    __shared__ float4 sS[NC];        // 4 KB boundary states
    __shared__ float wtot[4][12];    // per-wave scan totals (M 9 + d 3)
    const int c  = threadIdx.x;
    const int l  = c & 63;
    const int wv = c >> 6;

    const float DT = 0.001f;
    const float w  = omega_p[0];
    const float k1 = 1.0f + DT * (-0.3f);
    const float k2 = DT * 2.0f * w;
    const float k3 = DT * 1.65f;
    const float k4 = DT * 2.88f;
    const float kw = DT * w;
    const float kA = 1.0f + DT * (-0.15f);
    const float cc = 1.69705627484771f;
    const float nk4 = -k4, n2k4 = -2.0f * k4;
    const float w2c = 2.0f * w;

    // ---- predictor: 64 coarse Euler steps (dt=64DT) + (c&3) medium (dt=16DT)
    float vx = state0[2], vp = state0[3], cx = state0[4];
    float S0 = vx, S1 = vp, S2 = cx;
    {
        const int Q = c >> 2, r = c & 3;
        const float dt64 = 64.0f * DT;
        for (int i = 0; i < 64; ++i) {
            if (i == Q) { S0 = vx; S1 = vp; S2 = cx; }
            const float fvx = fmaf(-2.88f, vx * vx, fmaf(-0.3f, vx, fmaf(w2c, cx, 1.65f)));
            const float fvp = fmaf(-2.88f, cx * cx, fmaf(-0.3f, vp, fmaf(-w2c, cx, 1.65f)));
            const float fcx = fmaf(-2.88f, vx * cx, fmaf(-0.3f, cx, w * (vp - vx)));
            vx = fmaf(dt64, fvx, vx);
            vp = fmaf(dt64, fvp, vp);
            cx = fmaf(dt64, fcx, cx);
        }
        vx = S0; vp = S1; cx = S2;
        const float dt16 = 16.0f * DT;
        #pragma unroll
        for (int i = 0; i < 3; ++i) {
            if (i < r) {
                const float fvx = fmaf(-2.88f, vx * vx, fmaf(-0.3f, vx, fmaf(w2c, cx, 1.65f)));
                const float fvp = fmaf(-2.88f, cx * cx, fmaf(-0.3f, vp, fmaf(-w2c, cx, 1.65f)));
                const float fcx = fmaf(-2.88f, vx * cx, fmaf(-0.3f, cx, w * (vp - vx)));
                vx = fmaf(dt16, fvx, vx);
                vp = fmaf(dt16, fvp, vp);
                cx = fmaf(dt16, fcx, cx);
            }
        }
        S0 = vx; S1 = vp; S2 = cx;
    }
    sS[c] = make_float4(S0, S1, S2, 0.f);
    __syncthreads();

    // ---- Newton sweeps ----
    for (int sw = 0; sw < NSWEEP; ++sw) {
        float vx0 = S0, vp0 = S1, cx0 = S2;
        float m00=1.f,m01=0.f,m02=0.f, m10=0.f,m11=1.f,m12=0.f, m20=0.f,m21=0.f,m22=1.f;
        #pragma unroll 4
        for (int j = 0; j < CH; ++j) {
            const float J00 = fmaf(n2k4, vx0, k1);
            const float J12 = fmaf(n2k4, cx0, -k2);
            const float J20 = fmaf(nk4, cx0, -kw);
            const float J22 = fmaf(nk4, vx0, k1);
            const float a00 = fmaf(J00, m00, k2 * m20);
            const float a01 = fmaf(J00, m01, k2 * m21);
            const float a02 = fmaf(J00, m02, k2 * m22);
            const float a10 = fmaf(k1, m10, J12 * m20);
            const float a11 = fmaf(k1, m11, J12 * m21);
            const float a12 = fmaf(k1, m12, J12 * m22);
            const float a20 = fmaf(J20, m00, fmaf(kw, m10, J22 * m20));
            const float a21 = fmaf(J20, m01, fmaf(kw, m11, J22 * m21));
            const float a22 = fmaf(J20, m02, fmaf(kw, m12, J22 * m22));
            m00 = a00; m01 = a01; m02 = a02;
            m10 = a10; m11 = a11; m12 = a12;
            m20 = a20; m21 = a21; m22 = a22;
            const float t1   = fmaf(nk4, vx0, k1);
            const float s1   = fmaf(k2, cx0, k3);
            const float mvx  = -kw * vx0;
            const float mm   = fmaf(kw, vp0, mvx);
            const float cxp2 = cx0 * cx0;
            const float uu   = fmaf(-k2, cx0, k3);
            const float in2  = fmaf(nk4, cxp2, uu);
            const float nvp  = fmaf(k1, vp0, in2);
            const float nvx  = fmaf(t1, vx0, s1);
            const float ncx  = fmaf(t1, cx0, mm);
            vx0 = nvx; cx0 = ncx; vp0 = nvp;
        }
        const float4 Sn = sS[(c + 1) & (NC - 1)];
        float d0 = vx0 - Sn.x, d1 = vp0 - Sn.y, d2 = cx0 - Sn.z;
        if (c == NC - 1) { d0 = 0.f; d1 = 0.f; d2 = 0.f; }
        // intra-wave inclusive affine scan
        for (int k = 1; k < 64; k <<= 1) {
            const float o00 = __shfl_up(m00, k), o01 = __shfl_up(m01, k), o02 = __shfl_up(m02, k);
            const float o10 = __shfl_up(m10, k), o11 = __shfl_up(m11, k), o12 = __shfl_up(m12, k);
            const float o20 = __shfl_up(m20, k), o21 = __shfl_up(m21, k), o22 = __shfl_up(m22, k);
            const float e0  = __shfl_up(d0, k),  e1  = __shfl_up(d1, k),  e2  = __shfl_up(d2, k);
            if (l >= k) {
                const float b00 = fmaf(m00, o00, fmaf(m01, o10, m02 * o20));
                const float b01 = fmaf(m00, o01, fmaf(m01, o11, m02 * o21));
                const float b02 = fmaf(m00, o02, fmaf(m01, o12, m02 * o22));
                const float b10 = fmaf(m10, o00, fmaf(m11, o10, m12 * o20));
                const float b11 = fmaf(m10, o01, fmaf(m11, o11, m12 * o21));
                const float b12 = fmaf(m10, o02, fmaf(m11, o12, m12 * o22));
                const float b20 = fmaf(m20, o00, fmaf(m21, o10, m22 * o20));
                const float b21 = fmaf(m20, o01, fmaf(m21, o11, m22 * o21));
                const float b22 = fmaf(m20, o02, fmaf(m21, o12, m22 * o22));
                const float nd0 = fmaf(m00, e0, fmaf(m01, e1, fmaf(m02, e2, d0)));
                const float nd1 = fmaf(m10, e0, fmaf(m11, e1, fmaf(m12, e2, d1)));
                const float nd2 = fmaf(m20, e0, fmaf(m21, e1, fmaf(m22, e2, d2)));
                m00 = b00; m01 = b01; m02 = b02;
                m10 = b10; m11 = b11; m12 = b12;
                m20 = b20; m21 = b21; m22 = b22;
                d0 = nd0; d1 = nd1; d2 = nd2;
            }
        }
        if (l == 63) {
            float* wt = wtot[wv];
            wt[0]=m00; wt[1]=m01; wt[2]=m02; wt[3]=m10; wt[4]=m11; wt[5]=m12;
            wt[6]=m20; wt[7]=m21; wt[8]=m22; wt[9]=d0; wt[10]=d1; wt[11]=d2;
        }
        __syncthreads();
        // cross-wave: correction prefix needs only the q-component
        float pq0 = 0.f, pq1 = 0.f, pq2 = 0.f;
        for (int w2 = 0; w2 < wv; ++w2) {
            const float* wt = wtot[w2];
            const float n0 = fmaf(wt[0],pq0,fmaf(wt[1],pq1,fmaf(wt[2],pq2,wt[9])));
            const float n1 = fmaf(wt[3],pq0,fmaf(wt[4],pq1,fmaf(wt[5],pq2,wt[10])));
            const float n2 = fmaf(wt[6],pq0,fmaf(wt[7],pq1,fmaf(wt[8],pq2,wt[11])));
            pq0 = n0; pq1 = n1; pq2 = n2;
        }
        const float qf0 = fmaf(m00,pq0,fmaf(m01,pq1,fmaf(m02,pq2,d0)));
        const float qf1 = fmaf(m10,pq0,fmaf(m11,pq1,fmaf(m12,pq2,d1)));
        const float qf2 = fmaf(m20,pq0,fmaf(m21,pq1,fmaf(m22,pq2,d2)));
        float E0 = __shfl_up(qf0, 1), E1 = __shfl_up(qf1, 1), E2 = __shfl_up(qf2, 1);
        if (l == 0) { E0 = pq0; E1 = pq1; E2 = pq2; }
        S0 += E0; S1 += E1; S2 += E2;
        __syncthreads();                    // wtot reads done before next sweep writes
        sS[c] = make_float4(S0, S1, S2, 0.f);
        __syncthreads();
    }

    // ---- final pass: write scovT (own column), lane 255 writes fin ----
    float vx0 = S0, vp0 = S1, cx0 = S2;
    #pragma unroll 4
    for (int j = 0; j < CH; ++j) {
        scovT[j * NC + c] = make_float2(vx0, cx0);
        const float t1   = fmaf(nk4, vx0, k1);
        const float s1   = fmaf(k2, cx0, k3);
        const float mvx  = -kw * vx0;
        const float mm   = fmaf(kw, vp0, mvx);
        const float cxp2 = cx0 * cx0;
        const float uu   = fmaf(-k2, cx0, k3);
        const float in2  = fmaf(nk4, cxp2, uu);
        const float nvp  = fmaf(k1, vp0, in2);
        const float nvx  = fmaf(t1, vx0, s1);
        const float ncx  = fmaf(t1, cx0, mm);
        vx0 = nvx; cx0 = ncx; vp0 = nvp;
    }
    if (c == NC - 1) {
        ws[WS_F]     = vx0;
        ws[WS_F + 1] = vp0;
        ws[WS_F + 2] = cx0;
        ws[WS_F + 3] = state0[5] + 4096.0f * 0.001f;  // closed-form t (err <=5e-4)
    }

    // ---- backward pass over own 16-step chunk (coalesced table writes) ----
    float r00 = 1.f, r01 = 0.f, r10 = 0.f, r11 = 1.f;
    float4* TtabT = (float4*)(ws + WS_T);
    float2* HtabT = (float2*)(ws + WS_H);
    #pragma unroll 4
    for (int j = CH - 1; j >= 0; --j) {
        const float2 vc = scovT[j * NC + c];
        const float T00 = fmaf(nk4, vc.x, kA);
        const float T10 = fmaf(nk4, vc.y, -kw);
        const float g0  = cc * vc.x;
        const float g1  = cc * vc.y;
        HtabT[j * NC + c] = make_float2(fmaf(r00, g0, r01 * g1), fmaf(r10, g0, r11 * g1));
        TtabT[j * NC + c] = make_float4(T00, T10, g0, g1);
        const float n00 = fmaf(r00, T00, r01 * T10);
        const float n01 = fmaf(r00, kw,  r01 * kA);
        const float n10 = fmaf(r10, T00, r11 * T10);
        const float n11 = fmaf(r10, kw,  r11 * kA);
        r00 = n00; r01 = n01; r10 = n10; r11 = n11;
    }
    ((float4*)(ws + WS_P))[c] = make_float4(r00, r01, r10, r11);
}

__global__ __launch_bounds__(256) void grnn_phaseBCD(
    const float* __restrict__ dy,
    const float* __restrict__ state0,
    const float* __restrict__ omega_p,
    float* __restrict__ out,
    const float* __restrict__ ws)
{
    __shared__ float sbuf[CH * SB];    // 16.5 KB, [j*SB + c]
    __shared__ float wtot[4][6];       // per-wave (P,q) totals
    const int b  = blockIdx.x;
    const int c  = threadIdx.x;        // chunk index
    const int l  = c & 63;
    const int wv = c >> 6;

    const float DT = 0.001f;
    const float w  = omega_p[0];
    const float kw = DT * w;
    const float kA = 1.0f + DT * (-0.15f);
    const float cc = 1.69705627484771f;
    const float kcDT = cc * DT;

    const float4* TtabT = (const float4*)(ws + WS_T);
    const float2* HtabT = (const float2*)(ws + WS_H);

    // ---- stage in: coalesced float4 -> LDS transposed ----
    const float* dyb = dy + (size_t)b * (T * 2);
    #pragma unroll
    for (int k = 0; k < 8; ++k) {
        const float4 d = *(const float4*)(dyb + 4 * (k * 256 + c));
        const int t0 = 2 * (k * 256 + c);
        const int j0 = t0 & 15;
        const int c0 = t0 >> 4;
        sbuf[j0 * SB + c0]       = d.x;
        sbuf[(j0 + 1) * SB + c0] = d.z;
    }
    __syncthreads();

    // ---- phase B: q_c = sum_j H_j * dy0 ----
    float q0 = 0.f, q1 = 0.f;
    #pragma unroll 4
    for (int j = 0; j < CH; ++j) {
        const float d0 = sbuf[j * SB + c];
        const float2 h = HtabT[j * NC + c];
        q0 = fmaf(h.x, d0, q0);
        q1 = fmaf(h.y, d0, q1);
    }
    const float4 Pv = ((const float4*)(ws + WS_P))[c];
    float p00 = Pv.x, p01 = Pv.y, p10 = Pv.z, p11 = Pv.w;

    // ---- phase C: two-level affine scan over 256 chunks ----
    for (int d = 1; d < 64; d <<= 1) {
        const float o00 = __shfl_up(p00, d), o01 = __shfl_up(p01, d);
        const float o10 = __shfl_up(p10, d), o11 = __shfl_up(p11, d);
        const float oq0 = __shfl_up(q0, d),  oq1 = __shfl_up(q1, d);
        if (l >= d) {
            const float n00 = fmaf(p00, o00, p01 * o10);
            const float n01 = fmaf(p00, o01, p01 * o11);
            const float n10 = fmaf(p10, o00, p11 * o10);
            const float n11 = fmaf(p10, o01, p11 * o11);
            const float nq0 = fmaf(p00, oq0, fmaf(p01, oq1, q0));
            const float nq1 = fmaf(p10, oq0, fmaf(p11, oq1, q1));
            p00 = n00; p01 = n01; p10 = n10; p11 = n11;
            q0 = nq0; q1 = nq1;
        }
    }
    if (l == 63) {
        float* wt = wtot[wv];
        wt[0] = p00; wt[1] = p01; wt[2] = p10; wt[3] = p11; wt[4] = q0; wt[5] = q1;
    }
    __syncthreads();
    // wave-exclusive prefix (needs P and q: applied to x_init)
    float f00 = 1.f, f01 = 0.f, f10 = 0.f, f11 = 1.f, fq0 = 0.f, fq1 = 0.f;
    for (int w2 = 0; w2 < wv; ++w2) {
        const float* wt = wtot[w2];
        const float t00 = wt[0], t01 = wt[1], t10 = wt[2], t11 = wt[3];
        const float tq0 = wt[4], tq1 = wt[5];
        const float n00 = fmaf(t00, f00, t01 * f10);
        const float n01 = fmaf(t00, f01, t01 * f11);
        const float n10 = fmaf(t10, f00, t11 * f10);
        const float n11 = fmaf(t10, f01, t11 * f11);
        const float nq0 = fmaf(t00, fq0, fmaf(t01, fq1, tq0));
        const float nq1 = fmaf(t10, fq0, fmaf(t11, fq1, tq1));
        f00 = n00; f01 = n01; f10 = n10; f11 = n11; fq0 = nq0; fq1 = nq1;
    }
    // full inclusive at this lane, then exclusive via shfl_up
    const float F00 = fmaf(p00, f00, p01 * f10);
    const float F01 = fmaf(p00, f01, p01 * f11);
    const float F10 = fmaf(p10, f00, p11 * f10);
    const float F11 = fmaf(p10, f01, p11 * f11);
    const float Fq0 = fmaf(p00, fq0, fmaf(p01, fq1, q0));
    const float Fq1 = fmaf(p10, fq0, fmaf(p11, fq1, q1));
    float e00 = __shfl_up(F00, 1), e01 = __shfl_up(F01, 1);
    float e10 = __shfl_up(F10, 1), e11 = __shfl_up(F11, 1);
    float eq0 = __shfl_up(Fq0, 1), eq1 = __shfl_up(Fq1, 1);
    if (l == 0) { e00 = f00; e01 = f01; e10 = f10; e11 = f11; eq0 = fq0; eq1 = fq1; }

    const float xi0 = state0[b * 6 + 0];
    const float xi1 = state0[b * 6 + 1];
    float x0 = fmaf(e00, xi0, fmaf(e01, xi1, eq0));
    float x1 = fmaf(e10, xi0, fmaf(e11, xi1, eq1));

    // ---- phase D: re-walk 16 steps; write h back in place ----
    #pragma unroll 4
    for (int j = 0; j < CH; ++j) {
        const float d0 = sbuf[j * SB + c];
        const float4 Tt = TtabT[j * NC + c];
        const float h0  = kcDT * x0;
        const float nx0 = fmaf(Tt.x, x0, fmaf(kw, x1, Tt.z * d0));
        const float nx1 = fmaf(Tt.y, x0, fmaf(kA, x1, Tt.w * d0));
        sbuf[j * SB + c] = h0;
        x0 = nx0; x1 = nx1;
    }

    if (c == NC - 1) {
        float* os = out + b * 6;
        os[0] = x0;           os[1] = x1;
        os[2] = ws[WS_F];     os[3] = ws[WS_F + 1];
        os[4] = ws[WS_F + 2]; os[5] = ws[WS_F + 3];
    }
    __syncthreads();

    // ---- stage out: LDS -> coalesced float4 (h, 0, h, 0) ----
    float* dyh = out + B * 6 + (size_t)b * (T * 2);
    #pragma unroll
    for (int k = 0; k < 8; ++k) {
        const int t0 = 2 * (k * 256 + c);
        const int j0 = t0 & 15;
        const int c0 = t0 >> 4;
        const float h0 = sbuf[j0 * SB + c0];
        const float h1 = sbuf[(j0 + 1) * SB + c0];
        *(float4*)(dyh + 4 * (k * 256 + c)) = make_float4(h0, 0.f, h1, 0.f);
    }
}

extern "C" void kernel_launch(void* const* d_in, const int* in_sizes, int n_in,
                              void* d_out, int out_size, void* d_ws, size_t ws_size,
                              hipStream_t stream) {
    const float* dy     = (const float*)d_in[0];
    const float* state0 = (const float*)d_in[1];
    const float* omega  = (const float*)d_in[2];
    float* out = (float*)d_out;
    float* ws  = (float*)d_ws;
    grnn_phaseA<<<1, 256, 0, stream>>>(state0, omega, ws);
    grnn_phaseBCD<<<B, 256, 0, stream>>>(dy, state0, omega, out, ws);
}